// Round 2
// baseline (773.714 us; speedup 1.0000x reference)
//
#include <hip/hip_runtime.h>
#include <hip/hip_bf16.h>

typedef __attribute__((ext_vector_type(8))) short bf16x8;
typedef __attribute__((ext_vector_type(4))) float f32x4;

#define DIN 24
#define DOUT 47
#define CIN 32
#define COUT 64
#define SP_IN 13824
#define SP_OUT 103823
#define GROUPS 8
#define WPK_OFF 512

__device__ __forceinline__ float hswish(float z) {
    float c = fminf(fmaxf(z + 3.f, 0.f), 6.f);
    return z * c * (1.f / 6.f);
}

// Pack weights into per-fragment order: wpk[tap][coblk][lane][j] (bf16)
// A[row=co][k=ci]: lane -> co = coblk*16 + (lane&15), ci = (lane>>4)*8 + j
__global__ __launch_bounds__(256)
void repack_w(const float* __restrict__ w, unsigned short* __restrict__ wpk)
{
    int i = blockIdx.x * 256 + threadIdx.x;
    if (i >= 27 * 4 * 64 * 8) return;
    int j = i & 7;
    int lane = (i >> 3) & 63;
    int coblk = (i >> 9) & 3;
    int tap = i >> 11;
    int kw = tap % 3, kh = (tap / 3) % 3, kd = tap / 9;
    int co = coblk * 16 + (lane & 15);
    int ci = (lane >> 4) * 8 + j;
    float v = w[(((co * CIN + ci) * 3 + kd) * 3 + kh) * 3 + kw];
    __hip_bfloat16 h = __float2bfloat16(v);
    wpk[i] = *(const unsigned short*)&h;
}

// LDS x tile: 9 planes (dr,hr in 3x3), each 10 rows (wr 0..8 data, wr=9 zeros)
// of 40 bf16 (32 ci + 8 pad -> 80B stride, 16B aligned, bank-spread).
template<int PD, int PH>
__device__ __forceinline__ void conv_phase(
    const float* __restrict__ x, const unsigned short* __restrict__ wpk,
    const float* __restrict__ bias, float* __restrict__ y,
    float* __restrict__ stats, unsigned short* xs)
{
    constexpr int ND = PD ? 2 : 1;
    constexpr int NH = PH ? 2 : 1;
    constexpr int Na = 24 - PD;       // valid output count along a (od = 2a+PD)
    constexpr int Nb = 24 - PH;

    const int bx = blockIdx.x;        // 3 * 12 * 12
    const int tw = bx % 3;
    const int rest = bx / 3;
    const int b0 = (rest % 12) * 2;
    const int a0 = (rest / 12) * 2;
    const int ow0 = tw * 16;
    const int iw0 = tw * 8;
    const int n = blockIdx.z;
    const int tid = threadIdx.x;

    // ---- stage x tile (fp32 -> bf16) ----
    const float* xb = x + (size_t)n * CIN * SP_IN;
    for (int i = tid; i < 90 * 32; i += 256) {
        int ci = i & 31;
        int r = i >> 5;                // 0..89
        int wr = r % 10;
        int t2 = r / 10;
        int hr = t2 % 3;
        int dr = t2 / 3;
        float v = 0.f;
        if (wr < 9) {
            int id = min(a0 + dr, 23);
            int ih = min(b0 + hr, 23);
            int iw = min(iw0 + wr, 23);
            v = xb[ci * SP_IN + (id * DIN + ih) * DIN + iw];
        }
        __hip_bfloat16 h = __float2bfloat16(v);
        xs[r * 40 + ci] = *(const unsigned short*)&h;
    }
    __syncthreads();

    const int lane = tid & 63;
    const int wv = tid >> 6;          // wave = co block (16 co)
    const int col = lane & 15;        // MFMA column = ow offset
    const int kg = lane >> 4;         // k-group (8 ci)
    const int ow = ow0 + col;

    // B-operand LDS element offsets per kw (zero row loc=9 for invalid col/kw)
    int bo[3];
    #pragma unroll
    for (int kw = 0; kw < 3; ++kw) {
        int u = ow + 1 - kw;
        bool valid = ((u & 1) == 0) && (ow < DOUT);
        int loc = valid ? ((u >> 1) - iw0) : 9;   // in [0,8] when valid
        bo[kw] = loc * 40 + kg * 8;
    }

    f32x4 a00 = {0,0,0,0}, a01 = {0,0,0,0}, a10 = {0,0,0,0}, a11 = {0,0,0,0};

    #pragma unroll
    for (int dp = 0; dp < ND; ++dp) {
        const int kd = PD ? (dp ? 2 : 0) : 1;
        const int ad = PD ? (dp ? 0 : 1) : 0;     // id = a + ad
        #pragma unroll
        for (int hp = 0; hp < NH; ++hp) {
            const int kh = PH ? (hp ? 2 : 0) : 1;
            const int ah = PH ? (hp ? 0 : 1) : 0;
            #pragma unroll
            for (int kw = 0; kw < 3; ++kw) {
                const int tap = (kd * 3 + kh) * 3 + kw;
                const bf16x8 af =
                    *(const bf16x8*)&wpk[(size_t)((tap * 4 + wv) * 64 + lane) * 8];
                const int b = bo[kw];
                const bf16x8 b00 = *(const bf16x8*)&xs[(0 + ad) * 1200 + (0 + ah) * 400 + b];
                const bf16x8 b01 = *(const bf16x8*)&xs[(0 + ad) * 1200 + (1 + ah) * 400 + b];
                const bf16x8 b10 = *(const bf16x8*)&xs[(1 + ad) * 1200 + (0 + ah) * 400 + b];
                const bf16x8 b11 = *(const bf16x8*)&xs[(1 + ad) * 1200 + (1 + ah) * 400 + b];
                a00 = __builtin_amdgcn_mfma_f32_16x16x32_bf16(af, b00, a00, 0, 0, 0);
                a01 = __builtin_amdgcn_mfma_f32_16x16x32_bf16(af, b01, a01, 0, 0, 0);
                a10 = __builtin_amdgcn_mfma_f32_16x16x32_bf16(af, b10, a10, 0, 0, 0);
                a11 = __builtin_amdgcn_mfma_f32_16x16x32_bf16(af, b11, a11, 0, 0, 0);
            }
        }
    }

    // ---- epilogue: bias + swish + store + stats ----
    const f32x4 bv = *(const f32x4*)&bias[wv * 16 + kg * 4];
    float s1 = 0.f, s2 = 0.f;
    float* yb = y + ((size_t)n * COUT + wv * 16 + kg * 4) * SP_OUT;
    const bool vw = (ow < DOUT);

#define EPI(ACC, TA, TB) { \
    const int aa = a0 + TA, bb = b0 + TB; \
    const bool vv = vw && (aa < Na) && (bb < Nb); \
    const int od = 2 * aa + PD, oh = 2 * bb + PH; \
    const int sp = od * (DOUT * DOUT) + oh * DOUT + ow; \
    _Pragma("unroll") \
    for (int j = 0; j < 4; ++j) { \
        float v = ACC[j] + bv[j]; \
        float sw = v / (1.f + __expf(-v)); \
        if (vv) { yb[j * SP_OUT + sp] = sw; s1 += sw; s2 += sw * sw; } \
    } }

    EPI(a00, 0, 0)
    EPI(a01, 0, 1)
    EPI(a10, 1, 0)
    EPI(a11, 1, 1)
#undef EPI

    // rows 0-7 (kg<2) belong to group 2*wv, rows 8-15 to 2*wv+1
    #pragma unroll
    for (int off = 16; off; off >>= 1) {
        s1 += __shfl_down(s1, off);
        s2 += __shfl_down(s2, off);
    }
    if ((lane & 31) == 0) {
        const int g = wv * 2 + (lane >> 5);
        atomicAdd(&stats[(n * GROUPS + g) * 2 + 0], s1);
        atomicAdd(&stats[(n * GROUPS + g) * 2 + 1], s2);
    }
}

__global__ __launch_bounds__(256)
void conv_mfma(const float* __restrict__ x, const unsigned short* __restrict__ wpk,
               const float* __restrict__ bias, float* __restrict__ y,
               float* __restrict__ stats)
{
    __shared__ unsigned short xs[90 * 40];
    switch (blockIdx.y) {
        case 0: conv_phase<0, 0>(x, wpk, bias, y, stats, xs); break;
        case 1: conv_phase<0, 1>(x, wpk, bias, y, stats, xs); break;
        case 2: conv_phase<1, 0>(x, wpk, bias, y, stats, xs); break;
        default: conv_phase<1, 1>(x, wpk, bias, y, stats, xs); break;
    }
}

__global__ __launch_bounds__(256)
void norm_hswish(float* __restrict__ y, const float* __restrict__ stats)
{
    const int total4 = (8 * COUT * SP_OUT) / 4;
    const int grp4 = (8 * SP_OUT) / 4;
    const float inv_cnt = 1.0f / (8.0f * (float)SP_OUT);
    float4* p = (float4*)y;
    int idx = blockIdx.x * 256 + threadIdx.x;
    const int stride = gridDim.x * 256;
    for (int i = idx; i < total4; i += stride) {
        const int ng = i / grp4;
        const float m1 = stats[ng * 2 + 0] * inv_cnt;
        const float m2 = stats[ng * 2 + 1] * inv_cnt;
        const float var = m2 - m1 * m1;
        const float rstd = rsqrtf(var + 1e-5f);
        float4 v = p[i];
        v.x = hswish((v.x - m1) * rstd);
        v.y = hswish((v.y - m1) * rstd);
        v.z = hswish((v.z - m1) * rstd);
        v.w = hswish((v.w - m1) * rstd);
        p[i] = v;
    }
}

extern "C" void kernel_launch(void* const* d_in, const int* in_sizes, int n_in,
                              void* d_out, int out_size, void* d_ws, size_t ws_size,
                              hipStream_t stream)
{
    const float* x    = (const float*)d_in[0];
    const float* w    = (const float*)d_in[1];
    const float* bias = (const float*)d_in[2];
    float* y     = (float*)d_out;
    float* stats = (float*)d_ws;
    unsigned short* wpk = (unsigned short*)((char*)d_ws + WPK_OFF);

    hipMemsetAsync(d_ws, 0, 512, stream);
    repack_w<<<216, 256, 0, stream>>>(w, wpk);

    dim3 grid(3 * 12 * 12, 4, 8);
    conv_mfma<<<grid, 256, 0, stream>>>(x, wpk, bias, y, stats);

    norm_hswish<<<2048, 256, 0, stream>>>(y, stats);
}

// Round 3
// 176.595 us; speedup vs baseline: 4.3813x; 4.3813x over previous
//
#include <hip/hip_runtime.h>
#include <hip/hip_bf16.h>

typedef __attribute__((ext_vector_type(8))) short bf16x8;
typedef __attribute__((ext_vector_type(4))) float f32x4;

#define DIN 24
#define DOUT 47
#define CIN 32
#define COUT 64
#define SP_IN 13824
#define SP_OUT 103823
#define GROUPS 8
#define WPK_OFF 512
#define LROW 40          // elems per (plane,iw) row: 32 ci + 8 pad (80B, 16B-aligned)
#define PLANE 1000       // 25 * LROW elems per (id,ih) plane (iw 0..23 + zero slot 24)

__device__ __forceinline__ unsigned short f2bf(float v) {
    __hip_bfloat16 h = __float2bfloat16(v);
    return *(const unsigned short*)&h;
}

__device__ __forceinline__ float hswish(float z) {
    float c = fminf(fmaxf(z + 3.f, 0.f), 6.f);
    return z * c * (1.f / 6.f);
}

// wpk[tap][coblk][lane][j]: A-frag bf16, co = coblk*16+(lane&15), ci = (lane>>4)*8+j
__global__ __launch_bounds__(256)
void repack_w(const float* __restrict__ w, unsigned short* __restrict__ wpk)
{
    int i = blockIdx.x * 256 + threadIdx.x;
    if (i >= 27 * 4 * 64 * 8) return;
    int j = i & 7;
    int lane = (i >> 3) & 63;
    int coblk = (i >> 9) & 3;
    int tap = i >> 11;
    int kw = tap % 3, kh = (tap / 3) % 3, kd = tap / 9;
    int co = coblk * 16 + (lane & 15);
    int ci = (lane >> 4) * 8 + j;
    wpk[i] = f2bf(w[(((co * CIN + ci) * 3 + kd) * 3 + kh) * 3 + kw]);
}

__global__ __launch_bounds__(512)
void conv_mfma(const float* __restrict__ x, const unsigned short* __restrict__ wpk,
               const float* __restrict__ bias, float* __restrict__ y,
               float* __restrict__ stats)
{
    __shared__ unsigned short xs[15 * PLANE];   // 30000 B

    const int bx = blockIdx.x;                  // 12 d-tiles * 6 h-tiles
    const int t = bx / 6;                       // od slab [4t, 4t+4)
    const int s = bx - t * 6;                   // oh slab [8s, 8s+8)
    const int n = blockIdx.z;
    const int tid = threadIdx.x;

    // ---- stage x slab: planes (idl 0..2, ihl 0..4), fp32 -> bf16, transpose to [iw][ci]
    const float* xb = x + (size_t)n * (CIN * SP_IN);
    for (int i = tid; i < 2880; i += 512) {     // 480 rows * 6 float4
        int j = i % 6;
        int r = i / 6;
        int ci = r & 31;
        int pl = r >> 5;                        // 0..14
        int ihl = pl % 5, idl = pl / 5;
        int id = min(2 * t + idl, 23);
        int ih = min(4 * s + ihl, 23);
        const float4 v = *(const float4*)(xb + ci * SP_IN + (id * DIN + ih) * DIN + j * 4);
        int base = pl * PLANE + (j * 4) * LROW + ci;
        xs[base + 0 * LROW] = f2bf(v.x);
        xs[base + 1 * LROW] = f2bf(v.y);
        xs[base + 2 * LROW] = f2bf(v.z);
        xs[base + 3 * LROW] = f2bf(v.w);
    }
    for (int i = tid; i < 480; i += 512) {      // zero slot iw=24 per plane
        int ci = i & 31;
        int pl = i >> 5;
        xs[pl * PLANE + 24 * LROW + ci] = 0;
    }
    __syncthreads();

    const int lane = tid & 63;
    const int w8 = tid >> 6;
    const int cb = w8 & 3;                      // co block (16 co)
    const int hh = w8 >> 2;                     // oh half (4 oh each)
    const int col = lane & 15;
    const int kg = lane >> 4;

    // per-lane B row offsets (elems), zero slot for parity-invalid cols
    int pb[3][3];
    #pragma unroll
    for (int wt = 0; wt < 3; ++wt)
        #pragma unroll
        for (int kw = 0; kw < 3; ++kw) {
            int ow_ = wt * 16 + col;
            int u = ow_ + 1 - kw;
            bool valid = ((u & 1) == 0) && (ow_ < DOUT);
            int loc = valid ? (u >> 1) : 24;
            pb[wt][kw] = loc * LROW + kg * 8 + hh * 2000;   // + hh*2 planes
        }

    float s1 = 0.f, s2 = 0.f;
    const f32x4 bv = *(const f32x4*)&bias[cb * 16 + kg * 4];
    float* yb = y + ((size_t)n * COUT + cb * 16 + kg * 4) * SP_OUT;
    const unsigned short* wb = wpk + (size_t)cb * 512 + (size_t)lane * 8;  // +tap*2048

    auto epi = [&](const f32x4& a, int od, int oh, int wt) {
        int ow_ = wt * 16 + col;
        bool v = ow_ < DOUT;
        size_t sp = (size_t)od * (DOUT * DOUT) + oh * DOUT + ow_;
        #pragma unroll
        for (int j = 0; j < 4; ++j) {
            float vv = a[j] + bv[j];
            float sw = vv / (1.f + __expf(-vv));
            if (v) { yb[j * SP_OUT + sp] = sw; s1 += sw; s2 += sw * sw; }
        }
    };

#define MF3(A0, A1, A2, TAP, OFF) { \
    const bf16x8 af = *(const bf16x8*)&wb[(TAP) * 2048]; \
    A0 = __builtin_amdgcn_mfma_f32_16x16x32_bf16(af, *(const bf16x8*)&xs[pb[0][kw] + (OFF)], A0, 0, 0, 0); \
    A1 = __builtin_amdgcn_mfma_f32_16x16x32_bf16(af, *(const bf16x8*)&xs[pb[1][kw] + (OFF)], A1, 0, 0, 0); \
    A2 = __builtin_amdgcn_mfma_f32_16x16x32_bf16(af, *(const bf16x8*)&xs[pb[2][kw] + (OFF)], A2, 0, 0, 0); }

    const int od0 = 4 * t;
    const int ohb = 8 * s + 4 * hh;
    const bool sEdge = (s == 5) && (hh == 1);

    for (int e = 0; e < 2; ++e) {
        const int odE = od0 + 2 * e;
        const int odO = odE + 1;
        const bool odOv = (odO < DOUT);
        for (int f = 0; f < 2; ++f) {
            const int ohE = ohb + 2 * f;
            const int ohO = ohE + 1;
            const bool ohOv = !(sEdge && (f == 1));
            const int base = e * 5000 + f * 1000;

            {   // (odE, ohE): kd=1, kh=1
                f32x4 a0 = {0,0,0,0}, a1 = {0,0,0,0}, a2 = {0,0,0,0};
                #pragma unroll
                for (int kw = 0; kw < 3; ++kw) {
                    MF3(a0, a1, a2, 12 + kw, base)
                }
                epi(a0, odE, ohE, 0); epi(a1, odE, ohE, 1); epi(a2, odE, ohE, 2);
            }
            if (ohOv) {   // (odE, ohO): kd=1, kh in {0,2}
                f32x4 a0 = {0,0,0,0}, a1 = {0,0,0,0}, a2 = {0,0,0,0};
                #pragma unroll
                for (int kw = 0; kw < 3; ++kw) {
                    MF3(a0, a1, a2, 9 + kw,  base + 1000)   // kh=0 -> ihl+1
                    MF3(a0, a1, a2, 15 + kw, base)          // kh=2
                }
                epi(a0, odE, ohO, 0); epi(a1, odE, ohO, 1); epi(a2, odE, ohO, 2);
            }
            if (odOv) {   // (odO, ohE): kd in {0,2}, kh=1
                f32x4 a0 = {0,0,0,0}, a1 = {0,0,0,0}, a2 = {0,0,0,0};
                #pragma unroll
                for (int kw = 0; kw < 3; ++kw) {
                    MF3(a0, a1, a2, 3 + kw,  base + 5000)   // kd=0 -> idl+1
                    MF3(a0, a1, a2, 21 + kw, base)          // kd=2
                }
                epi(a0, odO, ohE, 0); epi(a1, odO, ohE, 1); epi(a2, odO, ohE, 2);
            }
            if (odOv && ohOv) {   // (odO, ohO): kd in {0,2}, kh in {0,2}
                f32x4 a0 = {0,0,0,0}, a1 = {0,0,0,0}, a2 = {0,0,0,0};
                #pragma unroll
                for (int kw = 0; kw < 3; ++kw) {
                    MF3(a0, a1, a2, 0 + kw,  base + 6000)   // kd=0,kh=0
                    MF3(a0, a1, a2, 6 + kw,  base + 5000)   // kd=0,kh=2
                    MF3(a0, a1, a2, 18 + kw, base + 1000)   // kd=2,kh=0
                    MF3(a0, a1, a2, 24 + kw, base)          // kd=2,kh=2
                }
                epi(a0, odO, ohO, 0); epi(a1, odO, ohO, 1); epi(a2, odO, ohO, 2);
            }
        }
    }
#undef MF3

    #pragma unroll
    for (int off = 16; off; off >>= 1) {
        s1 += __shfl_down(s1, off);
        s2 += __shfl_down(s2, off);
    }
    if ((lane & 31) == 0) {
        const int g = cb * 2 + (lane >> 5);
        atomicAdd(&stats[(n * GROUPS + g) * 2 + 0], s1);
        atomicAdd(&stats[(n * GROUPS + g) * 2 + 1], s2);
    }
}

__global__ __launch_bounds__(256)
void norm_hswish(float* __restrict__ y, const float* __restrict__ stats)
{
    const int total4 = (8 * COUT * SP_OUT) / 4;
    const int grp4 = (8 * SP_OUT) / 4;
    const float inv_cnt = 1.0f / (8.0f * (float)SP_OUT);
    float4* p = (float4*)y;
    int idx = blockIdx.x * 256 + threadIdx.x;
    const int stride = gridDim.x * 256;
    for (int i = idx; i < total4; i += stride) {
        const int ng = i / grp4;
        const float m1 = stats[ng * 2 + 0] * inv_cnt;
        const float m2 = stats[ng * 2 + 1] * inv_cnt;
        const float var = m2 - m1 * m1;
        const float rstd = rsqrtf(var + 1e-5f);
        float4 v = p[i];
        v.x = hswish((v.x - m1) * rstd);
        v.y = hswish((v.y - m1) * rstd);
        v.z = hswish((v.z - m1) * rstd);
        v.w = hswish((v.w - m1) * rstd);
        p[i] = v;
    }
}

extern "C" void kernel_launch(void* const* d_in, const int* in_sizes, int n_in,
                              void* d_out, int out_size, void* d_ws, size_t ws_size,
                              hipStream_t stream)
{
    const float* x    = (const float*)d_in[0];
    const float* w    = (const float*)d_in[1];
    const float* bias = (const float*)d_in[2];
    float* y     = (float*)d_out;
    float* stats = (float*)d_ws;
    unsigned short* wpk = (unsigned short*)((char*)d_ws + WPK_OFF);

    hipMemsetAsync(d_ws, 0, 512, stream);
    repack_w<<<216, 256, 0, stream>>>(w, wpk);

    dim3 grid(12 * 6, 1, 8);
    conv_mfma<<<grid, 512, 0, stream>>>(x, wpk, bias, y, stats);

    norm_hswish<<<2048, 256, 0, stream>>>(y, stats);
}